// Round 2
// baseline (282.149 us; speedup 1.0000x reference)
//
#include <hip/hip_runtime.h>

// GraphSAGE 2-layer. N=50000, E=800000, D_IN=128, D_H=256, D_OUT=128.
//
// R8: de-stage the fused GEMM. Weights (128 KB each, read identically by all
// 782 blocks) and the block's A-slice (L2-hot, written by gather1) are read
// straight from global/L2 as MFMA fragments; only H (64x264 bf16 = 33.8 KB)
// lives in LDS. This cuts LDS 79.9->33.8 KB (2->4 blocks/CU, 16 waves/CU) and
// barriers 16->1, removing the vmcnt(0)+barrier drain that left MfmaUtil at 7%.
// __launch_bounds__(256,4) caps VGPR at 128 for 4 waves/SIMD.
//
// Pipeline:
//   prep: Wc1/Wc2 bf16 pack | x->bf16 into A1 cols 128..255 | cnt=0 | off[N]=E
//   hist: rank[e] = cnt[dst[e]]++            (E int atomics, rank coalesced)
//   scan_blocks / scan_add: exclusive scan -> off
//   fill: csr[off[dst[e]] + rank[e]] = src[e]   (plain stores, 4 edges/thread)
//   gather1: A1 cols 0..127 = mean_{s in adj(n)} bf16(x[s])
//   gemm_fused: per 64-node block: H=relu(A1@Wc1.T+b1l) in LDS (reg accum);
//               t = H@W2l.T (bf16), out = H@W2r.T + b2l (fp32)
//   gather2: out[n] += mean_{s in adj(n)} t[s]     (node-owned RMW)
//
// Layer-2 trick: mean(h[src])@W2l.T == mean((h@W2l.T)[src]).

typedef __attribute__((ext_vector_type(8))) short bf16x8;
typedef __attribute__((ext_vector_type(4))) float floatx4;

__device__ inline unsigned short f2b(float f) {
  unsigned int x = __float_as_uint(f);
  unsigned int r = (x + 0x7fffu + ((x >> 16) & 1u)) >> 16;
  return (unsigned short)r;
}
__device__ inline float blo(unsigned int u) { return __uint_as_float(u << 16); }
__device__ inline float bhi(unsigned int u) { return __uint_as_float(u & 0xffff0000u); }

#define ACC8(A, u)                                            \
  {                                                           \
    A[0] += blo((u).x); A[1] += bhi((u).x);                   \
    A[2] += blo((u).y); A[3] += bhi((u).y);                   \
    A[4] += blo((u).z); A[5] += bhi((u).z);                   \
    A[6] += blo((u).w); A[7] += bhi((u).w);                   \
  }

// Fused prep: weight pack, x->bf16 convert, cnt zero, off[N]=E.
__global__ void prep_kernel(const float* __restrict__ x,
                            const float* __restrict__ W1l, const float* __restrict__ W1r,
                            const float* __restrict__ W2l, const float* __restrict__ W2r,
                            unsigned short* __restrict__ Wc1, unsigned short* __restrict__ Wc2,
                            unsigned short* __restrict__ A1,
                            int* __restrict__ cnt, int* __restrict__ off, int N, int E) {
  int i = blockIdx.x * blockDim.x + threadIdx.x;
  if (i < 65536) {
    int j = i >> 8, k = i & 255;
    float v1 = (k < 128) ? W1l[j * 128 + k] : W1r[j * 128 + (k - 128)];
    Wc1[i] = f2b(v1);
    float v2 = (j < 128) ? W2l[j * 256 + k] : W2r[(j - 128) * 256 + k];
    Wc2[i] = f2b(v2);
  }
  if (i < N) cnt[i] = 0;
  if (i == 0) off[N] = E;
  if (i < N * 32) {
    int n = i >> 5, c = (i & 31) * 4;
    float4 v = *(const float4*)(x + (size_t)n * 128 + c);
    uint2 p;
    p.x = (unsigned int)f2b(v.x) | ((unsigned int)f2b(v.y) << 16);
    p.y = (unsigned int)f2b(v.z) | ((unsigned int)f2b(v.w) << 16);
    *(uint2*)(A1 + (size_t)n * 256 + 128 + c) = p;
  }
}

// Histogram + per-edge rank capture (4 edges/thread, vectorized loads).
__global__ void hist_kernel(const int* __restrict__ dst, int* __restrict__ cnt,
                            int* __restrict__ rank, int E) {
  int i = blockIdx.x * blockDim.x + threadIdx.x;
  int e = i * 4;
  if (e + 3 < E) {
    int4 d = *(const int4*)(dst + e);
    int4 r;
    r.x = atomicAdd(&cnt[d.x], 1);
    r.y = atomicAdd(&cnt[d.y], 1);
    r.z = atomicAdd(&cnt[d.z], 1);
    r.w = atomicAdd(&cnt[d.w], 1);
    *(int4*)(rank + e) = r;
  } else {
    for (; e < E; e++) rank[e] = atomicAdd(&cnt[dst[e]], 1);
  }
}

// Per-1024-block exclusive scan; block total -> bsum[b].
__global__ __launch_bounds__(1024) void scan_blocks_kernel(const int* __restrict__ cnt,
                                                           int* __restrict__ off,
                                                           int* __restrict__ bsum, int N) {
  __shared__ int wsum[16];
  __shared__ int wincl[16];
  const int tid = threadIdx.x;
  const int lane = tid & 63;
  const int wv = tid >> 6;
  const int i = blockIdx.x * 1024 + tid;
  const int v = (i < N) ? cnt[i] : 0;
  int s = v;
#pragma unroll
  for (int o = 1; o < 64; o <<= 1) {
    int t = __shfl_up(s, o, 64);
    if (lane >= o) s += t;
  }
  if (lane == 63) wsum[wv] = s;
  __syncthreads();
  if (tid < 16) {
    int ws = wsum[tid];
#pragma unroll
    for (int o = 1; o < 16; o <<= 1) {
      int t = __shfl_up(ws, o, 16);
      if ((tid & 15) >= o) ws += t;
    }
    wincl[tid] = ws;
  }
  __syncthreads();
  const int wo = wv ? wincl[wv - 1] : 0;
  if (i < N) off[i] = wo + s - v;
  if (tid == 1023) bsum[blockIdx.x] = wo + s;
}

// Add block offsets (block-sum scan inlined: <=64 sums, wave 0).
__global__ __launch_bounds__(1024) void scan_add_kernel(int* __restrict__ off,
                                                        const int* __restrict__ bsum, int N, int SB) {
  __shared__ int bofs[64];
  const int tid = threadIdx.x;
  if (tid < 64) {
    int v = (tid < SB) ? bsum[tid] : 0;
    int s = v;
#pragma unroll
    for (int o = 1; o < 64; o <<= 1) {
      int t = __shfl_up(s, o, 64);
      if (tid >= o) s += t;
    }
    bofs[tid] = s - v;
  }
  __syncthreads();
  int i = blockIdx.x * 1024 + tid;
  if (i < N) off[i] = off[i] + bofs[blockIdx.x];
}

// Atomic-free fill: plain scattered stores, 4 edges/thread.
__global__ void fill_kernel(const int* __restrict__ src, const int* __restrict__ dst,
                            const int* __restrict__ rank, const int* __restrict__ off,
                            int* __restrict__ csr, int E) {
  int i = blockIdx.x * blockDim.x + threadIdx.x;
  int e = i * 4;
  if (e + 3 < E) {
    int4 d = *(const int4*)(dst + e);
    int4 r = *(const int4*)(rank + e);
    int4 s = *(const int4*)(src + e);
    csr[off[d.x] + r.x] = s.x;
    csr[off[d.y] + r.y] = s.y;
    csr[off[d.z] + r.z] = s.z;
    csr[off[d.w] + r.w] = s.w;
  } else {
    for (; e < E; e++) csr[off[dst[e]] + rank[e]] = src[e];
  }
}

// Gather-mean, one 64-lane wave per node. 8 slots x 8 lanes; each slot loads
// one edge's 256B row as 2 x uint4 half-rows; 2-edge unroll -> 16 edges per
// iteration with only 4 row-load instructions.
__global__ void gather1_kernel(const unsigned short* __restrict__ feat,
                               const int* __restrict__ csr, const int* __restrict__ off,
                               unsigned short* __restrict__ ob, int N) {
  int wid = (blockIdx.x * blockDim.x + threadIdx.x) >> 6;
  if (wid >= N) return;
  const int lane = threadIdx.x & 63;
  const int slot = lane >> 3;
  const int j = lane & 7;
  const int c0 = j * 8;  // bf16 col base within half-row
  const int s0 = off[wid], s1 = off[wid + 1];
  float a[16] = {};
  int e = s0 + slot;
  for (; e + 8 < s1; e += 16) {
    int i0 = csr[e], i1 = csr[e + 8];
    uint4 u0 = *(const uint4*)(feat + (size_t)i0 * 256 + c0);
    uint4 v0 = *(const uint4*)(feat + (size_t)i0 * 256 + 64 + c0);
    uint4 u1 = *(const uint4*)(feat + (size_t)i1 * 256 + c0);
    uint4 v1 = *(const uint4*)(feat + (size_t)i1 * 256 + 64 + c0);
    ACC8(a, u0); ACC8((a + 8), v0);
    ACC8(a, u1); ACC8((a + 8), v1);
  }
  for (; e < s1; e += 8) {
    int i0 = csr[e];
    uint4 u0 = *(const uint4*)(feat + (size_t)i0 * 256 + c0);
    uint4 v0 = *(const uint4*)(feat + (size_t)i0 * 256 + 64 + c0);
    ACC8(a, u0); ACC8((a + 8), v0);
  }
#pragma unroll
  for (int k = 0; k < 16; k++) {
    a[k] += __shfl_xor(a[k], 8, 64);
    a[k] += __shfl_xor(a[k], 16, 64);
    a[k] += __shfl_xor(a[k], 32, 64);
  }
  if (slot == 0) {
    const float inv = 1.0f / fmaxf((float)(s1 - s0), 1.0f);
    uint4 p;
    p.x = (unsigned int)f2b(a[0] * inv) | ((unsigned int)f2b(a[1] * inv) << 16);
    p.y = (unsigned int)f2b(a[2] * inv) | ((unsigned int)f2b(a[3] * inv) << 16);
    p.z = (unsigned int)f2b(a[4] * inv) | ((unsigned int)f2b(a[5] * inv) << 16);
    p.w = (unsigned int)f2b(a[6] * inv) | ((unsigned int)f2b(a[7] * inv) << 16);
    *(uint4*)(ob + (size_t)wid * 256 + c0) = p;
    p.x = (unsigned int)f2b(a[8] * inv) | ((unsigned int)f2b(a[9] * inv) << 16);
    p.y = (unsigned int)f2b(a[10] * inv) | ((unsigned int)f2b(a[11] * inv) << 16);
    p.z = (unsigned int)f2b(a[12] * inv) | ((unsigned int)f2b(a[13] * inv) << 16);
    p.w = (unsigned int)f2b(a[14] * inv) | ((unsigned int)f2b(a[15] * inv) << 16);
    *(uint4*)(ob + (size_t)wid * 256 + 64 + c0) = p;
  }
}

// Same structure; feat (t) stride 128 ushorts; accumulate into fp32 out.
__global__ void gather2_kernel(const unsigned short* __restrict__ t,
                               const int* __restrict__ csr, const int* __restrict__ off,
                               float* __restrict__ out, int N) {
  int wid = (blockIdx.x * blockDim.x + threadIdx.x) >> 6;
  if (wid >= N) return;
  const int lane = threadIdx.x & 63;
  const int slot = lane >> 3;
  const int j = lane & 7;
  const int c0 = j * 8;
  const int s0 = off[wid], s1 = off[wid + 1];
  float a[16] = {};
  int e = s0 + slot;
  for (; e + 8 < s1; e += 16) {
    int i0 = csr[e], i1 = csr[e + 8];
    uint4 u0 = *(const uint4*)(t + (size_t)i0 * 128 + c0);
    uint4 v0 = *(const uint4*)(t + (size_t)i0 * 128 + 64 + c0);
    uint4 u1 = *(const uint4*)(t + (size_t)i1 * 128 + c0);
    uint4 v1 = *(const uint4*)(t + (size_t)i1 * 128 + 64 + c0);
    ACC8(a, u0); ACC8((a + 8), v0);
    ACC8(a, u1); ACC8((a + 8), v1);
  }
  for (; e < s1; e += 8) {
    int i0 = csr[e];
    uint4 u0 = *(const uint4*)(t + (size_t)i0 * 128 + c0);
    uint4 v0 = *(const uint4*)(t + (size_t)i0 * 128 + 64 + c0);
    ACC8(a, u0); ACC8((a + 8), v0);
  }
#pragma unroll
  for (int k = 0; k < 16; k++) {
    a[k] += __shfl_xor(a[k], 8, 64);
    a[k] += __shfl_xor(a[k], 16, 64);
    a[k] += __shfl_xor(a[k], 32, 64);
  }
  if (slot == 0) {
    const float inv = 1.0f / fmaxf((float)(s1 - s0), 1.0f);
    float4* o0 = (float4*)(out + (size_t)wid * 128 + c0);
    float4* o1 = (float4*)(out + (size_t)wid * 128 + 64 + c0);
    float4 r0 = o0[0], r1 = o0[1], r2 = o1[0], r3 = o1[1];
    r0.x += a[0] * inv;  r0.y += a[1] * inv;  r0.z += a[2] * inv;  r0.w += a[3] * inv;
    r1.x += a[4] * inv;  r1.y += a[5] * inv;  r1.z += a[6] * inv;  r1.w += a[7] * inv;
    r2.x += a[8] * inv;  r2.y += a[9] * inv;  r2.z += a[10] * inv; r2.w += a[11] * inv;
    r3.x += a[12] * inv; r3.y += a[13] * inv; r3.z += a[14] * inv; r3.w += a[15] * inv;
    o0[0] = r0; o0[1] = r1; o1[0] = r2; o1[1] = r3;
  }
}

// Fused 2-layer bf16 MFMA GEMM, LDS-minimal. Per block: BM=64 nodes, BN=256.
// Phase A: acc = A1_blk @ Wc1.T (A,W frags straight from global/L2);
//          H = relu(acc+b1) -> Hs (bf16, stride 264; only LDS use). 1 barrier.
// Phase B: acc = Hs @ Wc2.T (W frags from global/L2);
//          j<128 -> tb = bf16(acc); j>=128 -> out = acc + b2l (fp32).
// 4 waves, each 64(m) x 64(n): 4x4 frags of mfma_f32_16x16x32_bf16.
// LDS 33.8 KB -> 4 blocks/CU; VGPR capped 128 -> 16 waves/CU.
__global__ __launch_bounds__(256, 4)
void gemm_fused(const unsigned short* __restrict__ A,
                const unsigned short* __restrict__ Wc1,
                const unsigned short* __restrict__ Wc2,
                const float* __restrict__ b1, const float* __restrict__ b2,
                unsigned short* __restrict__ tb, float* __restrict__ out, int M) {
  constexpr int LDH = 264;  // row stride 132 dw == 4 banks mod 32
  __shared__ __align__(16) unsigned short Hs[64 * LDH];
  const int t = threadIdx.x;
  const int lane = t & 63;
  const int wave = t >> 6;
  const int wn = wave * 64;
  const int l15 = lane & 15;
  const int quad = lane >> 4;
  const int m_blk = blockIdx.x * 64;

  // Per-lane base pointers (k-dim walks via +ks).
  const unsigned short* ap[4];
  const unsigned short* wp[4];
#pragma unroll
  for (int mt = 0; mt < 4; mt++) {
    int ar = m_blk + mt * 16 + l15;
    if (ar >= M) ar = M - 1;
    ap[mt] = A + (size_t)ar * 256 + quad * 8;
  }
#pragma unroll
  for (int nt = 0; nt < 4; nt++)
    wp[nt] = Wc1 + (size_t)(wn + nt * 16 + l15) * 256 + quad * 8;

  floatx4 acc[4][4] = {};

  // ---- Phase A: acc = A @ Wc1.T ----
#pragma unroll 2
  for (int ks = 0; ks < 256; ks += 32) {
    bf16x8 af[4], bfr[4];
#pragma unroll
    for (int mt = 0; mt < 4; mt++) af[mt] = *(const bf16x8*)(ap[mt] + ks);
#pragma unroll
    for (int nt = 0; nt < 4; nt++) bfr[nt] = *(const bf16x8*)(wp[nt] + ks);
#pragma unroll
    for (int mt = 0; mt < 4; mt++)
#pragma unroll
      for (int nt = 0; nt < 4; nt++)
        acc[mt][nt] = __builtin_amdgcn_mfma_f32_16x16x32_bf16(af[mt], bfr[nt], acc[mt][nt], 0, 0, 0);
  }

  // epilogue A: relu + bias, bf16, into Hs
#pragma unroll
  for (int nt = 0; nt < 4; nt++) {
    const int jl = wn + nt * 16 + l15;
    const float bv = b1[jl];
#pragma unroll
    for (int mt = 0; mt < 4; mt++) {
#pragma unroll
      for (int r = 0; r < 4; r++) {
        const int row = mt * 16 + quad * 4 + r;
        Hs[row * LDH + jl] = f2b(fmaxf(acc[mt][nt][r] + bv, 0.f));
      }
    }
  }
  __syncthreads();

  // ---- Phase B: acc = Hs @ Wc2.T ----
#pragma unroll
  for (int mt = 0; mt < 4; mt++)
#pragma unroll
    for (int nt = 0; nt < 4; nt++)
      acc[mt][nt] = (floatx4){0.f, 0.f, 0.f, 0.f};
#pragma unroll
  for (int nt = 0; nt < 4; nt++)
    wp[nt] = Wc2 + (size_t)(wn + nt * 16 + l15) * 256 + quad * 8;
  const unsigned short* hp0 = Hs + l15 * LDH + quad * 8;

#pragma unroll 2
  for (int ks = 0; ks < 256; ks += 32) {
    bf16x8 af[4], bfr[4];
#pragma unroll
    for (int mt = 0; mt < 4; mt++)
      af[mt] = *(const bf16x8*)(hp0 + mt * 16 * LDH + ks);
#pragma unroll
    for (int nt = 0; nt < 4; nt++) bfr[nt] = *(const bf16x8*)(wp[nt] + ks);
#pragma unroll
    for (int mt = 0; mt < 4; mt++)
#pragma unroll
      for (int nt = 0; nt < 4; nt++)
        acc[mt][nt] = __builtin_amdgcn_mfma_f32_16x16x32_bf16(af[mt], bfr[nt], acc[mt][nt], 0, 0, 0);
  }

  // epilogue B: waves 0,1 (j<128) -> tb bf16; waves 2,3 -> out fp32 + bias
#pragma unroll
  for (int nt = 0; nt < 4; nt++) {
    const int j = wn + nt * 16 + l15;
#pragma unroll
    for (int mt = 0; mt < 4; mt++) {
#pragma unroll
      for (int r = 0; r < 4; r++) {
        const int node = m_blk + mt * 16 + quad * 4 + r;
        if (node >= M) continue;
        const float v = acc[mt][nt][r];
        if (j < 128) {
          tb[(size_t)node * 128 + j] = f2b(v);
        } else {
          out[(size_t)node * 128 + (j - 128)] = v + b2[j - 128];
        }
      }
    }
  }
}

extern "C" void kernel_launch(void* const* d_in, const int* in_sizes, int n_in,
                              void* d_out, int out_size, void* d_ws, size_t ws_size,
                              hipStream_t stream) {
  const float* x   = (const float*)d_in[0];
  const int*  eidx = (const int*)d_in[1];
  const float* W1l = (const float*)d_in[2];
  const float* b1l = (const float*)d_in[3];
  const float* W1r = (const float*)d_in[4];
  const float* W2l = (const float*)d_in[5];
  const float* b2l = (const float*)d_in[6];
  const float* W2r = (const float*)d_in[7];
  float* out = (float*)d_out;

  const int N = in_sizes[0] / 128;
  const int E = in_sizes[1] / 2;
  const int* src = eidx;
  const int* dst = eidx + E;

  int* cnt  = (int*)d_ws;          // [N]
  int* off  = cnt + N;             // [N+1]
  int* bsum = off + N + 1;         // [64]
  int* rank = bsum + 64;           // [E]
  int* csr  = rank + E;            // [E]
  size_t ioff = ((size_t)(N + N + 1 + 64 + 2 * E) * 4 + 15) & ~(size_t)15;
  unsigned short* A1  = (unsigned short*)((char*)d_ws + ioff);  // [N][256]
  unsigned short* tb  = A1 + (size_t)N * 256;                   // [N][128]
  unsigned short* Wc1 = tb + (size_t)N * 128;                   // [256][256]
  unsigned short* Wc2 = Wc1 + 65536;                            // [256][256]

  const int SB = (N + 1023) / 1024;  // 49

  prep_kernel<<<(N * 32 + 255) / 256, 256, 0, stream>>>(x, W1l, W1r, W2l, W2r,
                                                        Wc1, Wc2, A1, cnt, off, N, E);
  hist_kernel<<<(E / 4 + 255) / 256, 256, 0, stream>>>(dst, cnt, rank, E);
  scan_blocks_kernel<<<SB, 1024, 0, stream>>>(cnt, off, bsum, N);
  scan_add_kernel<<<SB, 1024, 0, stream>>>(off, bsum, N, SB);
  fill_kernel<<<(E / 4 + 255) / 256, 256, 0, stream>>>(src, dst, rank, off, csr, E);

  const int gblocks = (N + 3) / 4;  // 1 wave (64 lanes) per node
  gather1_kernel<<<gblocks, 256, 0, stream>>>(A1 + 128, csr, off, A1, N);

  gemm_fused<<<(N + 63) / 64, 256, 0, stream>>>(A1, Wc1, Wc2, b1l, b2l, tb, out, N);

  gather2_kernel<<<gblocks, 256, 0, stream>>>(tb, csr, off, out, N);
}

// Round 3
// 275.806 us; speedup vs baseline: 1.0230x; 1.0230x over previous
//
#include <hip/hip_runtime.h>

// GraphSAGE 2-layer. N=50000, E=800000, D_IN=128, D_H=256, D_OUT=128.
//
// R9: register-resident-W GEMMs. R7 (LDS-staged, 16 barrier rounds) and R8
// (de-staged frags from L2) were both latency-bound (MfmaUtil 6-7%). New
// structure: 512-thread blocks, 8 waves, each wave owns 64 rows x 32 cols.
// W fragments (wr[2][8] = 64 VGPR) are loaded ONCE per block from L2 and
// stay in registers; the A-tile (64 rows x K=256, 32 KB) is staged once into
// padded LDS (stride 264 ushorts == 4 banks mod 32, conflict-free b128).
// Inner loop = ds_read + MFMA only; ONE barrier per block; no global loads
// in the loop. Fusion dropped (W1res+W2res would spill): H round-trips via
// L2 (G2 block b reads exactly what G1 block b wrote -> same XCD L2).
//
// Pipeline:
//   prep: Wc1/Wc2 bf16 pack | x->bf16 into A1 cols 128..255 | cnt=0 | off[N]=E
//   hist: rank[e] = cnt[dst[e]]++            (E int atomics, rank coalesced)
//   scan_blocks / scan_add: exclusive scan -> off
//   fill: csr[off[dst[e]] + rank[e]] = src[e]   (plain stores, 4 edges/thread)
//   gather1: A1 cols 0..127 = mean_{s in adj(n)} bf16(x[s])
//   gemm1: H = relu(A1@Wc1.T + b1)                 [N,256] bf16
//   gemm2: j<128: tb = H@W2l.T (bf16); j>=128: out = H@W2r.T + b2l (fp32)
//   gather2: out[n] += mean_{s in adj(n)} t[s]     (node-owned RMW)
//
// Layer-2 trick: mean(h[src])@W2l.T == mean((h@W2l.T)[src]).

typedef __attribute__((ext_vector_type(8))) short bf16x8;
typedef __attribute__((ext_vector_type(4))) float floatx4;

__device__ inline unsigned short f2b(float f) {
  unsigned int x = __float_as_uint(f);
  unsigned int r = (x + 0x7fffu + ((x >> 16) & 1u)) >> 16;
  return (unsigned short)r;
}
__device__ inline float blo(unsigned int u) { return __uint_as_float(u << 16); }
__device__ inline float bhi(unsigned int u) { return __uint_as_float(u & 0xffff0000u); }

#define ACC8(A, u)                                            \
  {                                                           \
    A[0] += blo((u).x); A[1] += bhi((u).x);                   \
    A[2] += blo((u).y); A[3] += bhi((u).y);                   \
    A[4] += blo((u).z); A[5] += bhi((u).z);                   \
    A[6] += blo((u).w); A[7] += bhi((u).w);                   \
  }

// Fused prep: weight pack, x->bf16 convert, cnt zero, off[N]=E.
__global__ void prep_kernel(const float* __restrict__ x,
                            const float* __restrict__ W1l, const float* __restrict__ W1r,
                            const float* __restrict__ W2l, const float* __restrict__ W2r,
                            unsigned short* __restrict__ Wc1, unsigned short* __restrict__ Wc2,
                            unsigned short* __restrict__ A1,
                            int* __restrict__ cnt, int* __restrict__ off, int N, int E) {
  int i = blockIdx.x * blockDim.x + threadIdx.x;
  if (i < 65536) {
    int j = i >> 8, k = i & 255;
    float v1 = (k < 128) ? W1l[j * 128 + k] : W1r[j * 128 + (k - 128)];
    Wc1[i] = f2b(v1);
    float v2 = (j < 128) ? W2l[j * 256 + k] : W2r[(j - 128) * 256 + k];
    Wc2[i] = f2b(v2);
  }
  if (i < N) cnt[i] = 0;
  if (i == 0) off[N] = E;
  if (i < N * 32) {
    int n = i >> 5, c = (i & 31) * 4;
    float4 v = *(const float4*)(x + (size_t)n * 128 + c);
    uint2 p;
    p.x = (unsigned int)f2b(v.x) | ((unsigned int)f2b(v.y) << 16);
    p.y = (unsigned int)f2b(v.z) | ((unsigned int)f2b(v.w) << 16);
    *(uint2*)(A1 + (size_t)n * 256 + 128 + c) = p;
  }
}

// Histogram + per-edge rank capture (4 edges/thread, vectorized loads).
__global__ void hist_kernel(const int* __restrict__ dst, int* __restrict__ cnt,
                            int* __restrict__ rank, int E) {
  int i = blockIdx.x * blockDim.x + threadIdx.x;
  int e = i * 4;
  if (e + 3 < E) {
    int4 d = *(const int4*)(dst + e);
    int4 r;
    r.x = atomicAdd(&cnt[d.x], 1);
    r.y = atomicAdd(&cnt[d.y], 1);
    r.z = atomicAdd(&cnt[d.z], 1);
    r.w = atomicAdd(&cnt[d.w], 1);
    *(int4*)(rank + e) = r;
  } else {
    for (; e < E; e++) rank[e] = atomicAdd(&cnt[dst[e]], 1);
  }
}

// Per-1024-block exclusive scan; block total -> bsum[b].
__global__ __launch_bounds__(1024) void scan_blocks_kernel(const int* __restrict__ cnt,
                                                           int* __restrict__ off,
                                                           int* __restrict__ bsum, int N) {
  __shared__ int wsum[16];
  __shared__ int wincl[16];
  const int tid = threadIdx.x;
  const int lane = tid & 63;
  const int wv = tid >> 6;
  const int i = blockIdx.x * 1024 + tid;
  const int v = (i < N) ? cnt[i] : 0;
  int s = v;
#pragma unroll
  for (int o = 1; o < 64; o <<= 1) {
    int t = __shfl_up(s, o, 64);
    if (lane >= o) s += t;
  }
  if (lane == 63) wsum[wv] = s;
  __syncthreads();
  if (tid < 16) {
    int ws = wsum[tid];
#pragma unroll
    for (int o = 1; o < 16; o <<= 1) {
      int t = __shfl_up(ws, o, 16);
      if ((tid & 15) >= o) ws += t;
    }
    wincl[tid] = ws;
  }
  __syncthreads();
  const int wo = wv ? wincl[wv - 1] : 0;
  if (i < N) off[i] = wo + s - v;
  if (tid == 1023) bsum[blockIdx.x] = wo + s;
}

// Add block offsets (block-sum scan inlined: <=64 sums, wave 0).
__global__ __launch_bounds__(1024) void scan_add_kernel(int* __restrict__ off,
                                                        const int* __restrict__ bsum, int N, int SB) {
  __shared__ int bofs[64];
  const int tid = threadIdx.x;
  if (tid < 64) {
    int v = (tid < SB) ? bsum[tid] : 0;
    int s = v;
#pragma unroll
    for (int o = 1; o < 64; o <<= 1) {
      int t = __shfl_up(s, o, 64);
      if (tid >= o) s += t;
    }
    bofs[tid] = s - v;
  }
  __syncthreads();
  int i = blockIdx.x * 1024 + tid;
  if (i < N) off[i] = off[i] + bofs[blockIdx.x];
}

// Atomic-free fill: plain scattered stores, 4 edges/thread.
__global__ void fill_kernel(const int* __restrict__ src, const int* __restrict__ dst,
                            const int* __restrict__ rank, const int* __restrict__ off,
                            int* __restrict__ csr, int E) {
  int i = blockIdx.x * blockDim.x + threadIdx.x;
  int e = i * 4;
  if (e + 3 < E) {
    int4 d = *(const int4*)(dst + e);
    int4 r = *(const int4*)(rank + e);
    int4 s = *(const int4*)(src + e);
    csr[off[d.x] + r.x] = s.x;
    csr[off[d.y] + r.y] = s.y;
    csr[off[d.z] + r.z] = s.z;
    csr[off[d.w] + r.w] = s.w;
  } else {
    for (; e < E; e++) csr[off[dst[e]] + rank[e]] = src[e];
  }
}

// Gather-mean, one 64-lane wave per node. 8 slots x 8 lanes; each slot loads
// one edge's 256B row as 2 x uint4 half-rows; 2-edge unroll -> 16 edges per
// iteration with only 4 row-load instructions.
__global__ void gather1_kernel(const unsigned short* __restrict__ feat,
                               const int* __restrict__ csr, const int* __restrict__ off,
                               unsigned short* __restrict__ ob, int N) {
  int wid = (blockIdx.x * blockDim.x + threadIdx.x) >> 6;
  if (wid >= N) return;
  const int lane = threadIdx.x & 63;
  const int slot = lane >> 3;
  const int j = lane & 7;
  const int c0 = j * 8;  // bf16 col base within half-row
  const int s0 = off[wid], s1 = off[wid + 1];
  float a[16] = {};
  int e = s0 + slot;
  for (; e + 8 < s1; e += 16) {
    int i0 = csr[e], i1 = csr[e + 8];
    uint4 u0 = *(const uint4*)(feat + (size_t)i0 * 256 + c0);
    uint4 v0 = *(const uint4*)(feat + (size_t)i0 * 256 + 64 + c0);
    uint4 u1 = *(const uint4*)(feat + (size_t)i1 * 256 + c0);
    uint4 v1 = *(const uint4*)(feat + (size_t)i1 * 256 + 64 + c0);
    ACC8(a, u0); ACC8((a + 8), v0);
    ACC8(a, u1); ACC8((a + 8), v1);
  }
  for (; e < s1; e += 8) {
    int i0 = csr[e];
    uint4 u0 = *(const uint4*)(feat + (size_t)i0 * 256 + c0);
    uint4 v0 = *(const uint4*)(feat + (size_t)i0 * 256 + 64 + c0);
    ACC8(a, u0); ACC8((a + 8), v0);
  }
#pragma unroll
  for (int k = 0; k < 16; k++) {
    a[k] += __shfl_xor(a[k], 8, 64);
    a[k] += __shfl_xor(a[k], 16, 64);
    a[k] += __shfl_xor(a[k], 32, 64);
  }
  if (slot == 0) {
    const float inv = 1.0f / fmaxf((float)(s1 - s0), 1.0f);
    uint4 p;
    p.x = (unsigned int)f2b(a[0] * inv) | ((unsigned int)f2b(a[1] * inv) << 16);
    p.y = (unsigned int)f2b(a[2] * inv) | ((unsigned int)f2b(a[3] * inv) << 16);
    p.z = (unsigned int)f2b(a[4] * inv) | ((unsigned int)f2b(a[5] * inv) << 16);
    p.w = (unsigned int)f2b(a[6] * inv) | ((unsigned int)f2b(a[7] * inv) << 16);
    *(uint4*)(ob + (size_t)wid * 256 + c0) = p;
    p.x = (unsigned int)f2b(a[8] * inv) | ((unsigned int)f2b(a[9] * inv) << 16);
    p.y = (unsigned int)f2b(a[10] * inv) | ((unsigned int)f2b(a[11] * inv) << 16);
    p.z = (unsigned int)f2b(a[12] * inv) | ((unsigned int)f2b(a[13] * inv) << 16);
    p.w = (unsigned int)f2b(a[14] * inv) | ((unsigned int)f2b(a[15] * inv) << 16);
    *(uint4*)(ob + (size_t)wid * 256 + 64 + c0) = p;
  }
}

// Same structure; feat (t) stride 128 ushorts; accumulate into fp32 out.
__global__ void gather2_kernel(const unsigned short* __restrict__ t,
                               const int* __restrict__ csr, const int* __restrict__ off,
                               float* __restrict__ out, int N) {
  int wid = (blockIdx.x * blockDim.x + threadIdx.x) >> 6;
  if (wid >= N) return;
  const int lane = threadIdx.x & 63;
  const int slot = lane >> 3;
  const int j = lane & 7;
  const int c0 = j * 8;
  const int s0 = off[wid], s1 = off[wid + 1];
  float a[16] = {};
  int e = s0 + slot;
  for (; e + 8 < s1; e += 16) {
    int i0 = csr[e], i1 = csr[e + 8];
    uint4 u0 = *(const uint4*)(t + (size_t)i0 * 128 + c0);
    uint4 v0 = *(const uint4*)(t + (size_t)i0 * 128 + 64 + c0);
    uint4 u1 = *(const uint4*)(t + (size_t)i1 * 128 + c0);
    uint4 v1 = *(const uint4*)(t + (size_t)i1 * 128 + 64 + c0);
    ACC8(a, u0); ACC8((a + 8), v0);
    ACC8(a, u1); ACC8((a + 8), v1);
  }
  for (; e < s1; e += 8) {
    int i0 = csr[e];
    uint4 u0 = *(const uint4*)(t + (size_t)i0 * 128 + c0);
    uint4 v0 = *(const uint4*)(t + (size_t)i0 * 128 + 64 + c0);
    ACC8(a, u0); ACC8((a + 8), v0);
  }
#pragma unroll
  for (int k = 0; k < 16; k++) {
    a[k] += __shfl_xor(a[k], 8, 64);
    a[k] += __shfl_xor(a[k], 16, 64);
    a[k] += __shfl_xor(a[k], 32, 64);
  }
  if (slot == 0) {
    const float inv = 1.0f / fmaxf((float)(s1 - s0), 1.0f);
    float4* o0 = (float4*)(out + (size_t)wid * 128 + c0);
    float4* o1 = (float4*)(out + (size_t)wid * 128 + 64 + c0);
    float4 r0 = o0[0], r1 = o0[1], r2 = o1[0], r3 = o1[1];
    r0.x += a[0] * inv;  r0.y += a[1] * inv;  r0.z += a[2] * inv;  r0.w += a[3] * inv;
    r1.x += a[4] * inv;  r1.y += a[5] * inv;  r1.z += a[6] * inv;  r1.w += a[7] * inv;
    r2.x += a[8] * inv;  r2.y += a[9] * inv;  r2.z += a[10] * inv; r2.w += a[11] * inv;
    r3.x += a[12] * inv; r3.y += a[13] * inv; r3.z += a[14] * inv; r3.w += a[15] * inv;
    o0[0] = r0; o0[1] = r1; o1[0] = r2; o1[1] = r3;
  }
}

// GEMM layer 1: H = relu(A @ Wc1.T + b1). A [M][256] bf16, Wc1 [256][256].
// 512 threads = 8 waves; wave w owns rows 0..63 x cols [w*32, w*32+32).
// W-frags register-resident (wr[2][8] = 64 VGPR, loaded once, L2-hot).
// A-tile staged once to padded LDS (LDA=264: 132 dw == 4 mod 32 banks).
// One barrier; inner loop is ds_read_b128 + MFMA only.
__global__ __launch_bounds__(512, 4)
void gemm1(const unsigned short* __restrict__ A, const unsigned short* __restrict__ Wc1,
           const float* __restrict__ b1, unsigned short* __restrict__ H, int M) {
  constexpr int LDA = 264;
  __shared__ __align__(16) unsigned short As[64 * LDA];
  const int t = threadIdx.x;
  const int lane = t & 63;
  const int wave = t >> 6;
  const int wn = wave * 32;
  const int l15 = lane & 15;
  const int quad = lane >> 4;
  const int m_blk = blockIdx.x * 64;

  // Resident W fragments: j = wn + nt*16 + l15, k = c*32 + quad*8.
  bf16x8 wr[2][8];
#pragma unroll
  for (int nt = 0; nt < 2; nt++) {
    const unsigned short* wp = Wc1 + (size_t)(wn + nt * 16 + l15) * 256 + quad * 8;
#pragma unroll
    for (int c = 0; c < 8; c++) wr[nt][c] = *(const bf16x8*)(wp + c * 32);
  }
  const float bv0 = b1[wn + l15];
  const float bv1 = b1[wn + 16 + l15];

  // Stage A tile (64 rows x 256 k = 32 KB).
#pragma unroll
  for (int i = 0; i < 4; i++) {
    int idx = t + 512 * i;
    int row = idx >> 5, cc = (idx & 31) * 8;
    int ar = m_blk + row;
    if (ar >= M) ar = M - 1;
    *(uint4*)(As + row * LDA + cc) = *(const uint4*)(A + (size_t)ar * 256 + cc);
  }
  __syncthreads();

  floatx4 acc[4][2] = {};
#pragma unroll
  for (int c = 0; c < 8; c++) {
    bf16x8 af[4];
#pragma unroll
    for (int mt = 0; mt < 4; mt++)
      af[mt] = *(const bf16x8*)(As + (mt * 16 + l15) * LDA + c * 32 + quad * 8);
#pragma unroll
    for (int mt = 0; mt < 4; mt++) {
      acc[mt][0] = __builtin_amdgcn_mfma_f32_16x16x32_bf16(af[mt], wr[0][c], acc[mt][0], 0, 0, 0);
      acc[mt][1] = __builtin_amdgcn_mfma_f32_16x16x32_bf16(af[mt], wr[1][c], acc[mt][1], 0, 0, 0);
    }
  }

#pragma unroll
  for (int mt = 0; mt < 4; mt++) {
#pragma unroll
    for (int nt = 0; nt < 2; nt++) {
      const int j = wn + nt * 16 + l15;
      const float bv = nt ? bv1 : bv0;
#pragma unroll
      for (int r = 0; r < 4; r++) {
        const int node = m_blk + mt * 16 + quad * 4 + r;
        if (node < M) H[(size_t)node * 256 + j] = f2b(fmaxf(acc[mt][nt][r] + bv, 0.f));
      }
    }
  }
}

// GEMM layer 2: acc = H @ Wc2.T. Waves 0-3 (j<128): tb = bf16(acc) (=h@W2l.T);
// waves 4-7 (j>=128): out = acc + b2 (=h@W2r.T + b2l, fp32).
__global__ __launch_bounds__(512, 4)
void gemm2(const unsigned short* __restrict__ H, const unsigned short* __restrict__ Wc2,
           const float* __restrict__ b2, unsigned short* __restrict__ tb,
           float* __restrict__ out, int M) {
  constexpr int LDA = 264;
  __shared__ __align__(16) unsigned short As[64 * LDA];
  const int t = threadIdx.x;
  const int lane = t & 63;
  const int wave = t >> 6;
  const int wn = wave * 32;
  const int l15 = lane & 15;
  const int quad = lane >> 4;
  const int m_blk = blockIdx.x * 64;

  bf16x8 wr[2][8];
#pragma unroll
  for (int nt = 0; nt < 2; nt++) {
    const unsigned short* wp = Wc2 + (size_t)(wn + nt * 16 + l15) * 256 + quad * 8;
#pragma unroll
    for (int c = 0; c < 8; c++) wr[nt][c] = *(const bf16x8*)(wp + c * 32);
  }
  const float bv0 = (wn >= 128) ? b2[wn - 128 + l15] : 0.f;
  const float bv1 = (wn >= 128) ? b2[wn - 112 + l15] : 0.f;

#pragma unroll
  for (int i = 0; i < 4; i++) {
    int idx = t + 512 * i;
    int row = idx >> 5, cc = (idx & 31) * 8;
    int ar = m_blk + row;
    if (ar >= M) ar = M - 1;
    *(uint4*)(As + row * LDA + cc) = *(const uint4*)(H + (size_t)ar * 256 + cc);
  }
  __syncthreads();

  floatx4 acc[4][2] = {};
#pragma unroll
  for (int c = 0; c < 8; c++) {
    bf16x8 af[4];
#pragma unroll
    for (int mt = 0; mt < 4; mt++)
      af[mt] = *(const bf16x8*)(As + (mt * 16 + l15) * LDA + c * 32 + quad * 8);
#pragma unroll
    for (int mt = 0; mt < 4; mt++) {
      acc[mt][0] = __builtin_amdgcn_mfma_f32_16x16x32_bf16(af[mt], wr[0][c], acc[mt][0], 0, 0, 0);
      acc[mt][1] = __builtin_amdgcn_mfma_f32_16x16x32_bf16(af[mt], wr[1][c], acc[mt][1], 0, 0, 0);
    }
  }

#pragma unroll
  for (int mt = 0; mt < 4; mt++) {
#pragma unroll
    for (int nt = 0; nt < 2; nt++) {
      const int j = wn + nt * 16 + l15;
      const float bv = nt ? bv1 : bv0;
#pragma unroll
      for (int r = 0; r < 4; r++) {
        const int node = m_blk + mt * 16 + quad * 4 + r;
        if (node >= M) continue;
        const float v = acc[mt][nt][r];
        if (j < 128) {
          tb[(size_t)node * 128 + j] = f2b(v);
        } else {
          out[(size_t)node * 128 + (j - 128)] = v + bv;
        }
      }
    }
  }
}

extern "C" void kernel_launch(void* const* d_in, const int* in_sizes, int n_in,
                              void* d_out, int out_size, void* d_ws, size_t ws_size,
                              hipStream_t stream) {
  const float* x   = (const float*)d_in[0];
  const int*  eidx = (const int*)d_in[1];
  const float* W1l = (const float*)d_in[2];
  const float* b1l = (const float*)d_in[3];
  const float* W1r = (const float*)d_in[4];
  const float* W2l = (const float*)d_in[5];
  const float* b2l = (const float*)d_in[6];
  const float* W2r = (const float*)d_in[7];
  float* out = (float*)d_out;

  const int N = in_sizes[0] / 128;
  const int E = in_sizes[1] / 2;
  const int* src = eidx;
  const int* dst = eidx + E;

  int* cnt  = (int*)d_ws;          // [N]
  int* off  = cnt + N;             // [N+1]
  int* bsum = off + N + 1;         // [64]
  int* rank = bsum + 64;           // [E]
  int* csr  = rank + E;            // [E]
  size_t ioff = ((size_t)(N + N + 1 + 64 + 2 * E) * 4 + 15) & ~(size_t)15;
  unsigned short* A1  = (unsigned short*)((char*)d_ws + ioff);  // [N][256]
  unsigned short* h   = A1 + (size_t)N * 256;                   // [N][256]
  unsigned short* tb  = h + (size_t)N * 256;                    // [N][128]
  unsigned short* Wc1 = tb + (size_t)N * 128;                   // [256][256]
  unsigned short* Wc2 = Wc1 + 65536;                            // [256][256]

  const int SB = (N + 1023) / 1024;  // 49

  prep_kernel<<<(N * 32 + 255) / 256, 256, 0, stream>>>(x, W1l, W1r, W2l, W2r,
                                                        Wc1, Wc2, A1, cnt, off, N, E);
  hist_kernel<<<(E / 4 + 255) / 256, 256, 0, stream>>>(dst, cnt, rank, E);
  scan_blocks_kernel<<<SB, 1024, 0, stream>>>(cnt, off, bsum, N);
  scan_add_kernel<<<SB, 1024, 0, stream>>>(off, bsum, N, SB);
  fill_kernel<<<(E / 4 + 255) / 256, 256, 0, stream>>>(src, dst, rank, off, csr, E);

  const int gblocks = (N + 3) / 4;  // 1 wave (64 lanes) per node
  gather1_kernel<<<gblocks, 256, 0, stream>>>(A1 + 128, csr, off, A1, N);

  const int mblocks = (N + 63) / 64;  // 782
  gemm1<<<mblocks, 512, 0, stream>>>(A1, Wc1, b1l, h, N);
  gemm2<<<mblocks, 512, 0, stream>>>(h, Wc2, b2l, tb, out, N);

  gather2_kernel<<<gblocks, 256, 0, stream>>>(tb, csr, off, out, N);
}

// Round 4
// 267.770 us; speedup vs baseline: 1.0537x; 1.0300x over previous
//
#include <hip/hip_runtime.h>

// GraphSAGE 2-layer. N=50000, E=800000, D_IN=128, D_H=256, D_OUT=128.
//
// R10: (a) gathers rebuilt as 64-lanes-per-edge: each lane owns 2 columns
// (1 dword of the 256B row), so all edges accumulate in-register with ZERO
// cross-lane reduction tail (was 96 VALU ops/lane), perfectly coalesced
// 1-dword/lane row loads, 4-edge unroll for load ILP, packed dword stores.
// Edge ids broadcast from a lane-parallel csr read via __shfl.
// (b) GEMMs re-fused with sequential W-residency: phase A (reg-resident W1
// frags x LDS A-tile) -> H into LDS; reload same wr regs with W2 frags;
// phase B reads H from LDS. 2 barriers, no global loads in MFMA loops,
// h round-trip (51 MB) and one launch eliminated. LDS 67.6 KB -> 2 blk/CU.
//
// Pipeline:
//   prep: Wc1/Wc2 bf16 pack | x->bf16 into A1 cols 128..255 | cnt=0 | off[N]=E
//   hist: rank[e] = cnt[dst[e]]++            (E int atomics, rank coalesced)
//   scan_blocks / scan_add: exclusive scan -> off
//   fill: csr[off[dst[e]] + rank[e]] = src[e]   (plain stores, 4 edges/thread)
//   gather1: A1 cols 0..127 = mean_{s in adj(n)} bf16(x[s])
//   gemm_fused: H=relu(A1@Wc1.T+b1) in LDS; tb=H@W2l.T (bf16);
//               out=H@W2r.T+b2l (fp32)
//   gather2: out[n] += mean_{s in adj(n)} tb[s]    (node-owned RMW)
//
// Layer-2 trick: mean(h[src])@W2l.T == mean((h@W2l.T)[src]).

typedef __attribute__((ext_vector_type(8))) short bf16x8;
typedef __attribute__((ext_vector_type(4))) float floatx4;

__device__ inline unsigned short f2b(float f) {
  unsigned int x = __float_as_uint(f);
  unsigned int r = (x + 0x7fffu + ((x >> 16) & 1u)) >> 16;
  return (unsigned short)r;
}
__device__ inline float blo(unsigned int u) { return __uint_as_float(u << 16); }
__device__ inline float bhi(unsigned int u) { return __uint_as_float(u & 0xffff0000u); }

// Fused prep: weight pack, x->bf16 convert, cnt zero, off[N]=E.
__global__ void prep_kernel(const float* __restrict__ x,
                            const float* __restrict__ W1l, const float* __restrict__ W1r,
                            const float* __restrict__ W2l, const float* __restrict__ W2r,
                            unsigned short* __restrict__ Wc1, unsigned short* __restrict__ Wc2,
                            unsigned short* __restrict__ A1,
                            int* __restrict__ cnt, int* __restrict__ off, int N, int E) {
  int i = blockIdx.x * blockDim.x + threadIdx.x;
  if (i < 65536) {
    int j = i >> 8, k = i & 255;
    float v1 = (k < 128) ? W1l[j * 128 + k] : W1r[j * 128 + (k - 128)];
    Wc1[i] = f2b(v1);
    float v2 = (j < 128) ? W2l[j * 256 + k] : W2r[(j - 128) * 256 + k];
    Wc2[i] = f2b(v2);
  }
  if (i < N) cnt[i] = 0;
  if (i == 0) off[N] = E;
  if (i < N * 32) {
    int n = i >> 5, c = (i & 31) * 4;
    float4 v = *(const float4*)(x + (size_t)n * 128 + c);
    uint2 p;
    p.x = (unsigned int)f2b(v.x) | ((unsigned int)f2b(v.y) << 16);
    p.y = (unsigned int)f2b(v.z) | ((unsigned int)f2b(v.w) << 16);
    *(uint2*)(A1 + (size_t)n * 256 + 128 + c) = p;
  }
}

// Histogram + per-edge rank capture (4 edges/thread, vectorized loads).
__global__ void hist_kernel(const int* __restrict__ dst, int* __restrict__ cnt,
                            int* __restrict__ rank, int E) {
  int i = blockIdx.x * blockDim.x + threadIdx.x;
  int e = i * 4;
  if (e + 3 < E) {
    int4 d = *(const int4*)(dst + e);
    int4 r;
    r.x = atomicAdd(&cnt[d.x], 1);
    r.y = atomicAdd(&cnt[d.y], 1);
    r.z = atomicAdd(&cnt[d.z], 1);
    r.w = atomicAdd(&cnt[d.w], 1);
    *(int4*)(rank + e) = r;
  } else {
    for (; e < E; e++) rank[e] = atomicAdd(&cnt[dst[e]], 1);
  }
}

// Per-1024-block exclusive scan; block total -> bsum[b].
__global__ __launch_bounds__(1024) void scan_blocks_kernel(const int* __restrict__ cnt,
                                                           int* __restrict__ off,
                                                           int* __restrict__ bsum, int N) {
  __shared__ int wsum[16];
  __shared__ int wincl[16];
  const int tid = threadIdx.x;
  const int lane = tid & 63;
  const int wv = tid >> 6;
  const int i = blockIdx.x * 1024 + tid;
  const int v = (i < N) ? cnt[i] : 0;
  int s = v;
#pragma unroll
  for (int o = 1; o < 64; o <<= 1) {
    int t = __shfl_up(s, o, 64);
    if (lane >= o) s += t;
  }
  if (lane == 63) wsum[wv] = s;
  __syncthreads();
  if (tid < 16) {
    int ws = wsum[tid];
#pragma unroll
    for (int o = 1; o < 16; o <<= 1) {
      int t = __shfl_up(ws, o, 16);
      if ((tid & 15) >= o) ws += t;
    }
    wincl[tid] = ws;
  }
  __syncthreads();
  const int wo = wv ? wincl[wv - 1] : 0;
  if (i < N) off[i] = wo + s - v;
  if (tid == 1023) bsum[blockIdx.x] = wo + s;
}

// Add block offsets (block-sum scan inlined: <=64 sums, wave 0).
__global__ __launch_bounds__(1024) void scan_add_kernel(int* __restrict__ off,
                                                        const int* __restrict__ bsum, int N, int SB) {
  __shared__ int bofs[64];
  const int tid = threadIdx.x;
  if (tid < 64) {
    int v = (tid < SB) ? bsum[tid] : 0;
    int s = v;
#pragma unroll
    for (int o = 1; o < 64; o <<= 1) {
      int t = __shfl_up(s, o, 64);
      if (tid >= o) s += t;
    }
    bofs[tid] = s - v;
  }
  __syncthreads();
  int i = blockIdx.x * 1024 + tid;
  if (i < N) off[i] = off[i] + bofs[blockIdx.x];
}

// Atomic-free fill: plain scattered stores, 4 edges/thread.
__global__ void fill_kernel(const int* __restrict__ src, const int* __restrict__ dst,
                            const int* __restrict__ rank, const int* __restrict__ off,
                            int* __restrict__ csr, int E) {
  int i = blockIdx.x * blockDim.x + threadIdx.x;
  int e = i * 4;
  if (e + 3 < E) {
    int4 d = *(const int4*)(dst + e);
    int4 r = *(const int4*)(rank + e);
    int4 s = *(const int4*)(src + e);
    csr[off[d.x] + r.x] = s.x;
    csr[off[d.y] + r.y] = s.y;
    csr[off[d.z] + r.z] = s.z;
    csr[off[d.w] + r.w] = s.w;
  } else {
    for (; e < E; e++) csr[off[dst[e]] + rank[e]] = src[e];
  }
}

// Gather-mean, one wave per node, 64 lanes per edge-row. Lane l owns columns
// 2l,2l+1 (one dword of the 256B row): no cross-lane reduction; coalesced
// 1-dword/lane loads; 4-edge unroll for ILP. Edge ids via lane-parallel csr
// read + __shfl broadcast. feat stride 256 ushorts; out packed dword.
__global__ void gather1_kernel(const unsigned short* __restrict__ feat,
                               const int* __restrict__ csr, const int* __restrict__ off,
                               unsigned short* __restrict__ ob, int N) {
  int wid = (blockIdx.x * blockDim.x + threadIdx.x) >> 6;
  if (wid >= N) return;
  const int lane = threadIdx.x & 63;
  const int s0 = off[wid], s1 = off[wid + 1];
  float a0 = 0.f, a1 = 0.f;
  for (int base = s0; base < s1; base += 64) {
    const int cnt = min(64, s1 - base);
    int my = (lane < cnt) ? csr[base + lane] : 0;
    int k = 0;
    for (; k + 4 <= cnt; k += 4) {
      int i0 = __shfl(my, k);
      int i1 = __shfl(my, k + 1);
      int i2 = __shfl(my, k + 2);
      int i3 = __shfl(my, k + 3);
      unsigned u0 = ((const unsigned*)(feat + (size_t)i0 * 256))[lane];
      unsigned u1 = ((const unsigned*)(feat + (size_t)i1 * 256))[lane];
      unsigned u2 = ((const unsigned*)(feat + (size_t)i2 * 256))[lane];
      unsigned u3 = ((const unsigned*)(feat + (size_t)i3 * 256))[lane];
      a0 += blo(u0); a1 += bhi(u0);
      a0 += blo(u1); a1 += bhi(u1);
      a0 += blo(u2); a1 += bhi(u2);
      a0 += blo(u3); a1 += bhi(u3);
    }
    for (; k < cnt; k++) {
      int i0 = __shfl(my, k);
      unsigned u0 = ((const unsigned*)(feat + (size_t)i0 * 256))[lane];
      a0 += blo(u0); a1 += bhi(u0);
    }
  }
  const float inv = 1.0f / fmaxf((float)(s1 - s0), 1.0f);
  unsigned p = (unsigned)f2b(a0 * inv) | ((unsigned)f2b(a1 * inv) << 16);
  ((unsigned*)(ob + (size_t)wid * 256))[lane] = p;
}

// Same structure; feat (tb) stride 128 ushorts; accumulate into fp32 out
// (lane l RMWs float2 at cols 2l,2l+1).
__global__ void gather2_kernel(const unsigned short* __restrict__ t,
                               const int* __restrict__ csr, const int* __restrict__ off,
                               float* __restrict__ out, int N) {
  int wid = (blockIdx.x * blockDim.x + threadIdx.x) >> 6;
  if (wid >= N) return;
  const int lane = threadIdx.x & 63;
  const int s0 = off[wid], s1 = off[wid + 1];
  float a0 = 0.f, a1 = 0.f;
  for (int base = s0; base < s1; base += 64) {
    const int cnt = min(64, s1 - base);
    int my = (lane < cnt) ? csr[base + lane] : 0;
    int k = 0;
    for (; k + 4 <= cnt; k += 4) {
      int i0 = __shfl(my, k);
      int i1 = __shfl(my, k + 1);
      int i2 = __shfl(my, k + 2);
      int i3 = __shfl(my, k + 3);
      unsigned u0 = ((const unsigned*)(t + (size_t)i0 * 128))[lane];
      unsigned u1 = ((const unsigned*)(t + (size_t)i1 * 128))[lane];
      unsigned u2 = ((const unsigned*)(t + (size_t)i2 * 128))[lane];
      unsigned u3 = ((const unsigned*)(t + (size_t)i3 * 128))[lane];
      a0 += blo(u0); a1 += bhi(u0);
      a0 += blo(u1); a1 += bhi(u1);
      a0 += blo(u2); a1 += bhi(u2);
      a0 += blo(u3); a1 += bhi(u3);
    }
    for (; k < cnt; k++) {
      int i0 = __shfl(my, k);
      unsigned u0 = ((const unsigned*)(t + (size_t)i0 * 128))[lane];
      a0 += blo(u0); a1 += bhi(u0);
    }
  }
  const float inv = 1.0f / fmaxf((float)(s1 - s0), 1.0f);
  float2* op = (float2*)(out + (size_t)wid * 128) + lane;
  float2 r = *op;
  r.x += a0 * inv;
  r.y += a1 * inv;
  *op = r;
}

// Fused 2-layer bf16 MFMA GEMM, sequential W-residency. 512 thr = 8 waves;
// wave w owns rows 0..63 x cols [w*32, w*32+32). Phase A: wr=W1 frags (64
// VGPR, loaded once from L2), A-tile staged to LDS (LDA=264, conflict-free
// b128); H=relu(acc+b1) -> Hs (LDS). Reload wr=W2 frags; phase B: acc=Hs@W2.T;
// waves 0-3: tb=bf16(acc) (=h@W2l.T); waves 4-7: out=acc+b2 (fp32).
// 2 barriers; no global loads inside MFMA loops.
__global__ __launch_bounds__(512, 4)
void gemm_fused(const unsigned short* __restrict__ A, const unsigned short* __restrict__ Wc1,
                const unsigned short* __restrict__ Wc2,
                const float* __restrict__ b1, const float* __restrict__ b2,
                unsigned short* __restrict__ tb, float* __restrict__ out, int M) {
  constexpr int LDA = 264;
  __shared__ __align__(16) unsigned short As[64 * LDA];
  __shared__ __align__(16) unsigned short Hs[64 * LDA];
  const int t = threadIdx.x;
  const int lane = t & 63;
  const int wave = t >> 6;
  const int wn = wave * 32;
  const int l15 = lane & 15;
  const int quad = lane >> 4;
  const int m_blk = blockIdx.x * 64;

  // Resident W1 fragments: j = wn + nt*16 + l15, k = c*32 + quad*8.
  bf16x8 wr[2][8];
#pragma unroll
  for (int nt = 0; nt < 2; nt++) {
    const unsigned short* wp = Wc1 + (size_t)(wn + nt * 16 + l15) * 256 + quad * 8;
#pragma unroll
    for (int c = 0; c < 8; c++) wr[nt][c] = *(const bf16x8*)(wp + c * 32);
  }
  const float bv0 = b1[wn + l15];
  const float bv1 = b1[wn + 16 + l15];

  // Stage A tile (64 rows x 256 k = 32 KB).
#pragma unroll
  for (int i = 0; i < 4; i++) {
    int idx = t + 512 * i;
    int row = idx >> 5, cc = (idx & 31) * 8;
    int ar = m_blk + row;
    if (ar >= M) ar = M - 1;
    *(uint4*)(As + row * LDA + cc) = *(const uint4*)(A + (size_t)ar * 256 + cc);
  }
  __syncthreads();

  // ---- Phase A: acc = A @ Wc1.T ----
  floatx4 acc[4][2] = {};
#pragma unroll
  for (int c = 0; c < 8; c++) {
    bf16x8 af[4];
#pragma unroll
    for (int mt = 0; mt < 4; mt++)
      af[mt] = *(const bf16x8*)(As + (mt * 16 + l15) * LDA + c * 32 + quad * 8);
#pragma unroll
    for (int mt = 0; mt < 4; mt++) {
      acc[mt][0] = __builtin_amdgcn_mfma_f32_16x16x32_bf16(af[mt], wr[0][c], acc[mt][0], 0, 0, 0);
      acc[mt][1] = __builtin_amdgcn_mfma_f32_16x16x32_bf16(af[mt], wr[1][c], acc[mt][1], 0, 0, 0);
    }
  }

  // Epilogue A: H = relu(acc + b1) into Hs.
#pragma unroll
  for (int mt = 0; mt < 4; mt++) {
#pragma unroll
    for (int nt = 0; nt < 2; nt++) {
      const int jl = wn + nt * 16 + l15;
      const float bv = nt ? bv1 : bv0;
#pragma unroll
      for (int r = 0; r < 4; r++) {
        const int row = mt * 16 + quad * 4 + r;
        Hs[row * LDA + jl] = f2b(fmaxf(acc[mt][nt][r] + bv, 0.f));
      }
    }
  }

  // Reload wr with W2 fragments (independent of Hs; overlaps other waves'
  // epilogue work before the barrier).
#pragma unroll
  for (int nt = 0; nt < 2; nt++) {
    const unsigned short* wp = Wc2 + (size_t)(wn + nt * 16 + l15) * 256 + quad * 8;
#pragma unroll
    for (int c = 0; c < 8; c++) wr[nt][c] = *(const bf16x8*)(wp + c * 32);
  }
  const float cv0 = (wn >= 128) ? b2[wn - 128 + l15] : 0.f;
  const float cv1 = (wn >= 128) ? b2[wn - 112 + l15] : 0.f;
  __syncthreads();

  // ---- Phase B: acc = Hs @ Wc2.T ----
#pragma unroll
  for (int mt = 0; mt < 4; mt++) {
    acc[mt][0] = (floatx4){0.f, 0.f, 0.f, 0.f};
    acc[mt][1] = (floatx4){0.f, 0.f, 0.f, 0.f};
  }
#pragma unroll
  for (int c = 0; c < 8; c++) {
    bf16x8 af[4];
#pragma unroll
    for (int mt = 0; mt < 4; mt++)
      af[mt] = *(const bf16x8*)(Hs + (mt * 16 + l15) * LDA + c * 32 + quad * 8);
#pragma unroll
    for (int mt = 0; mt < 4; mt++) {
      acc[mt][0] = __builtin_amdgcn_mfma_f32_16x16x32_bf16(af[mt], wr[0][c], acc[mt][0], 0, 0, 0);
      acc[mt][1] = __builtin_amdgcn_mfma_f32_16x16x32_bf16(af[mt], wr[1][c], acc[mt][1], 0, 0, 0);
    }
  }

  // Epilogue B: waves 0-3 (j<128) -> tb bf16; waves 4-7 -> out fp32 + bias.
#pragma unroll
  for (int mt = 0; mt < 4; mt++) {
#pragma unroll
    for (int nt = 0; nt < 2; nt++) {
      const int j = wn + nt * 16 + l15;
      const float bv = nt ? cv1 : cv0;
#pragma unroll
      for (int r = 0; r < 4; r++) {
        const int node = m_blk + mt * 16 + quad * 4 + r;
        if (node >= M) continue;
        const float v = acc[mt][nt][r];
        if (j < 128) {
          tb[(size_t)node * 128 + j] = f2b(v);
        } else {
          out[(size_t)node * 128 + (j - 128)] = v + bv;
        }
      }
    }
  }
}

extern "C" void kernel_launch(void* const* d_in, const int* in_sizes, int n_in,
                              void* d_out, int out_size, void* d_ws, size_t ws_size,
                              hipStream_t stream) {
  const float* x   = (const float*)d_in[0];
  const int*  eidx = (const int*)d_in[1];
  const float* W1l = (const float*)d_in[2];
  const float* b1l = (const float*)d_in[3];
  const float* W1r = (const float*)d_in[4];
  const float* W2l = (const float*)d_in[5];
  const float* b2l = (const float*)d_in[6];
  const float* W2r = (const float*)d_in[7];
  float* out = (float*)d_out;

  const int N = in_sizes[0] / 128;
  const int E = in_sizes[1] / 2;
  const int* src = eidx;
  const int* dst = eidx + E;

  int* cnt  = (int*)d_ws;          // [N]
  int* off  = cnt + N;             // [N+1]
  int* bsum = off + N + 1;         // [64]
  int* rank = bsum + 64;           // [E]
  int* csr  = rank + E;            // [E]
  size_t ioff = ((size_t)(N + N + 1 + 64 + 2 * E) * 4 + 15) & ~(size_t)15;
  unsigned short* A1  = (unsigned short*)((char*)d_ws + ioff);  // [N][256]
  unsigned short* tb  = A1 + (size_t)N * 256;                   // [N][128]
  unsigned short* Wc1 = tb + (size_t)N * 128;                   // [256][256]
  unsigned short* Wc2 = Wc1 + 65536;                            // [256][256]

  const int SB = (N + 1023) / 1024;  // 49

  prep_kernel<<<(N * 32 + 255) / 256, 256, 0, stream>>>(x, W1l, W1r, W2l, W2r,
                                                        Wc1, Wc2, A1, cnt, off, N, E);
  hist_kernel<<<(E / 4 + 255) / 256, 256, 0, stream>>>(dst, cnt, rank, E);
  scan_blocks_kernel<<<SB, 1024, 0, stream>>>(cnt, off, bsum, N);
  scan_add_kernel<<<SB, 1024, 0, stream>>>(off, bsum, N, SB);
  fill_kernel<<<(E / 4 + 255) / 256, 256, 0, stream>>>(src, dst, rank, off, csr, E);

  const int gblocks = (N + 3) / 4;  // 1 wave (64 lanes) per node
  gather1_kernel<<<gblocks, 256, 0, stream>>>(A1 + 128, csr, off, A1, N);

  gemm_fused<<<(N + 63) / 64, 512, 0, stream>>>(A1, Wc1, Wc2, b1l, b2l, tb, out, N);

  gather2_kernel<<<gblocks, 256, 0, stream>>>(tb, csr, off, out, N);
}

// Round 5
// 266.095 us; speedup vs baseline: 1.0603x; 1.0063x over previous
//
#include <hip/hip_runtime.h>

// GraphSAGE 2-layer. N=50000, E=800000, D_IN=128, D_H=256, D_OUT=128.
//
// R11: gather MLP. R10's 64-lane-per-edge gathers only kept 4 row-loads in
// flight; with ~500cy L2/L3 latency and deg~16 the wave critical path was
// 4 latency exposures. Now 8-edge unroll (8 outstanding 256B row reads),
// 2-edge mid-tail, and gather2 prefetches its fp32 out row BEFORE the
// accumulate loop (was a serialized latency on every wave's tail).
// gemm_fused unchanged from R10 (fused, sequential W-residency).
//
// Pipeline:
//   prep: Wc1/Wc2 bf16 pack | x->bf16 into A1 cols 128..255 | cnt=0 | off[N]=E
//   hist: rank[e] = cnt[dst[e]]++            (E int atomics, rank coalesced)
//   scan_blocks / scan_add: exclusive scan -> off
//   fill: csr[off[dst[e]] + rank[e]] = src[e]   (plain stores, 4 edges/thread)
//   gather1: A1 cols 0..127 = mean_{s in adj(n)} bf16(x[s])
//   gemm_fused: H=relu(A1@Wc1.T+b1) in LDS; tb=H@W2l.T (bf16);
//               out=H@W2r.T+b2l (fp32)
//   gather2: out[n] += mean_{s in adj(n)} tb[s]    (node-owned RMW)
//
// Layer-2 trick: mean(h[src])@W2l.T == mean((h@W2l.T)[src]).

typedef __attribute__((ext_vector_type(8))) short bf16x8;
typedef __attribute__((ext_vector_type(4))) float floatx4;

__device__ inline unsigned short f2b(float f) {
  unsigned int x = __float_as_uint(f);
  unsigned int r = (x + 0x7fffu + ((x >> 16) & 1u)) >> 16;
  return (unsigned short)r;
}
__device__ inline float blo(unsigned int u) { return __uint_as_float(u << 16); }
__device__ inline float bhi(unsigned int u) { return __uint_as_float(u & 0xffff0000u); }

// Fused prep: weight pack, x->bf16 convert, cnt zero, off[N]=E.
__global__ void prep_kernel(const float* __restrict__ x,
                            const float* __restrict__ W1l, const float* __restrict__ W1r,
                            const float* __restrict__ W2l, const float* __restrict__ W2r,
                            unsigned short* __restrict__ Wc1, unsigned short* __restrict__ Wc2,
                            unsigned short* __restrict__ A1,
                            int* __restrict__ cnt, int* __restrict__ off, int N, int E) {
  int i = blockIdx.x * blockDim.x + threadIdx.x;
  if (i < 65536) {
    int j = i >> 8, k = i & 255;
    float v1 = (k < 128) ? W1l[j * 128 + k] : W1r[j * 128 + (k - 128)];
    Wc1[i] = f2b(v1);
    float v2 = (j < 128) ? W2l[j * 256 + k] : W2r[(j - 128) * 256 + k];
    Wc2[i] = f2b(v2);
  }
  if (i < N) cnt[i] = 0;
  if (i == 0) off[N] = E;
  if (i < N * 32) {
    int n = i >> 5, c = (i & 31) * 4;
    float4 v = *(const float4*)(x + (size_t)n * 128 + c);
    uint2 p;
    p.x = (unsigned int)f2b(v.x) | ((unsigned int)f2b(v.y) << 16);
    p.y = (unsigned int)f2b(v.z) | ((unsigned int)f2b(v.w) << 16);
    *(uint2*)(A1 + (size_t)n * 256 + 128 + c) = p;
  }
}

// Histogram + per-edge rank capture (4 edges/thread, vectorized loads).
__global__ void hist_kernel(const int* __restrict__ dst, int* __restrict__ cnt,
                            int* __restrict__ rank, int E) {
  int i = blockIdx.x * blockDim.x + threadIdx.x;
  int e = i * 4;
  if (e + 3 < E) {
    int4 d = *(const int4*)(dst + e);
    int4 r;
    r.x = atomicAdd(&cnt[d.x], 1);
    r.y = atomicAdd(&cnt[d.y], 1);
    r.z = atomicAdd(&cnt[d.z], 1);
    r.w = atomicAdd(&cnt[d.w], 1);
    *(int4*)(rank + e) = r;
  } else {
    for (; e < E; e++) rank[e] = atomicAdd(&cnt[dst[e]], 1);
  }
}

// Per-1024-block exclusive scan; block total -> bsum[b].
__global__ __launch_bounds__(1024) void scan_blocks_kernel(const int* __restrict__ cnt,
                                                           int* __restrict__ off,
                                                           int* __restrict__ bsum, int N) {
  __shared__ int wsum[16];
  __shared__ int wincl[16];
  const int tid = threadIdx.x;
  const int lane = tid & 63;
  const int wv = tid >> 6;
  const int i = blockIdx.x * 1024 + tid;
  const int v = (i < N) ? cnt[i] : 0;
  int s = v;
#pragma unroll
  for (int o = 1; o < 64; o <<= 1) {
    int t = __shfl_up(s, o, 64);
    if (lane >= o) s += t;
  }
  if (lane == 63) wsum[wv] = s;
  __syncthreads();
  if (tid < 16) {
    int ws = wsum[tid];
#pragma unroll
    for (int o = 1; o < 16; o <<= 1) {
      int t = __shfl_up(ws, o, 16);
      if ((tid & 15) >= o) ws += t;
    }
    wincl[tid] = ws;
  }
  __syncthreads();
  const int wo = wv ? wincl[wv - 1] : 0;
  if (i < N) off[i] = wo + s - v;
  if (tid == 1023) bsum[blockIdx.x] = wo + s;
}

// Add block offsets (block-sum scan inlined: <=64 sums, wave 0).
__global__ __launch_bounds__(1024) void scan_add_kernel(int* __restrict__ off,
                                                        const int* __restrict__ bsum, int N, int SB) {
  __shared__ int bofs[64];
  const int tid = threadIdx.x;
  if (tid < 64) {
    int v = (tid < SB) ? bsum[tid] : 0;
    int s = v;
#pragma unroll
    for (int o = 1; o < 64; o <<= 1) {
      int t = __shfl_up(s, o, 64);
      if (tid >= o) s += t;
    }
    bofs[tid] = s - v;
  }
  __syncthreads();
  int i = blockIdx.x * 1024 + tid;
  if (i < N) off[i] = off[i] + bofs[blockIdx.x];
}

// Atomic-free fill: plain scattered stores, 4 edges/thread.
__global__ void fill_kernel(const int* __restrict__ src, const int* __restrict__ dst,
                            const int* __restrict__ rank, const int* __restrict__ off,
                            int* __restrict__ csr, int E) {
  int i = blockIdx.x * blockDim.x + threadIdx.x;
  int e = i * 4;
  if (e + 3 < E) {
    int4 d = *(const int4*)(dst + e);
    int4 r = *(const int4*)(rank + e);
    int4 s = *(const int4*)(src + e);
    csr[off[d.x] + r.x] = s.x;
    csr[off[d.y] + r.y] = s.y;
    csr[off[d.z] + r.z] = s.z;
    csr[off[d.w] + r.w] = s.w;
  } else {
    for (; e < E; e++) csr[off[dst[e]] + rank[e]] = src[e];
  }
}

// Gather-mean, one wave per node, 64 lanes per edge-row. Lane l owns columns
// 2l,2l+1 (one dword of the 256B row): no cross-lane reduction; coalesced
// 1-dword/lane loads. 8-edge unroll -> 8 row-loads outstanding (latency
// cover); 2-edge mid-tail. Edge ids via lane-parallel csr read + __shfl.
__global__ void gather1_kernel(const unsigned short* __restrict__ feat,
                               const int* __restrict__ csr, const int* __restrict__ off,
                               unsigned short* __restrict__ ob, int N) {
  int wid = (blockIdx.x * blockDim.x + threadIdx.x) >> 6;
  if (wid >= N) return;
  const int lane = threadIdx.x & 63;
  const int s0 = off[wid], s1 = off[wid + 1];
  float a0 = 0.f, a1 = 0.f;
  for (int base = s0; base < s1; base += 64) {
    const int cnt = min(64, s1 - base);
    int my = (lane < cnt) ? csr[base + lane] : 0;
    int k = 0;
    for (; k + 8 <= cnt; k += 8) {
      int i0 = __shfl(my, k);
      int i1 = __shfl(my, k + 1);
      int i2 = __shfl(my, k + 2);
      int i3 = __shfl(my, k + 3);
      int i4 = __shfl(my, k + 4);
      int i5 = __shfl(my, k + 5);
      int i6 = __shfl(my, k + 6);
      int i7 = __shfl(my, k + 7);
      unsigned u0 = ((const unsigned*)(feat + (size_t)i0 * 256))[lane];
      unsigned u1 = ((const unsigned*)(feat + (size_t)i1 * 256))[lane];
      unsigned u2 = ((const unsigned*)(feat + (size_t)i2 * 256))[lane];
      unsigned u3 = ((const unsigned*)(feat + (size_t)i3 * 256))[lane];
      unsigned u4 = ((const unsigned*)(feat + (size_t)i4 * 256))[lane];
      unsigned u5 = ((const unsigned*)(feat + (size_t)i5 * 256))[lane];
      unsigned u6 = ((const unsigned*)(feat + (size_t)i6 * 256))[lane];
      unsigned u7 = ((const unsigned*)(feat + (size_t)i7 * 256))[lane];
      a0 += blo(u0); a1 += bhi(u0);
      a0 += blo(u1); a1 += bhi(u1);
      a0 += blo(u2); a1 += bhi(u2);
      a0 += blo(u3); a1 += bhi(u3);
      a0 += blo(u4); a1 += bhi(u4);
      a0 += blo(u5); a1 += bhi(u5);
      a0 += blo(u6); a1 += bhi(u6);
      a0 += blo(u7); a1 += bhi(u7);
    }
    for (; k + 2 <= cnt; k += 2) {
      int i0 = __shfl(my, k);
      int i1 = __shfl(my, k + 1);
      unsigned u0 = ((const unsigned*)(feat + (size_t)i0 * 256))[lane];
      unsigned u1 = ((const unsigned*)(feat + (size_t)i1 * 256))[lane];
      a0 += blo(u0); a1 += bhi(u0);
      a0 += blo(u1); a1 += bhi(u1);
    }
    if (k < cnt) {
      int i0 = __shfl(my, k);
      unsigned u0 = ((const unsigned*)(feat + (size_t)i0 * 256))[lane];
      a0 += blo(u0); a1 += bhi(u0);
    }
  }
  const float inv = 1.0f / fmaxf((float)(s1 - s0), 1.0f);
  unsigned p = (unsigned)f2b(a0 * inv) | ((unsigned)f2b(a1 * inv) << 16);
  ((unsigned*)(ob + (size_t)wid * 256))[lane] = p;
}

// Same structure; feat (tb) stride 128 ushorts; accumulate into fp32 out.
// out row prefetched BEFORE the loop (overlaps gather latency).
__global__ void gather2_kernel(const unsigned short* __restrict__ t,
                               const int* __restrict__ csr, const int* __restrict__ off,
                               float* __restrict__ out, int N) {
  int wid = (blockIdx.x * blockDim.x + threadIdx.x) >> 6;
  if (wid >= N) return;
  const int lane = threadIdx.x & 63;
  const int s0 = off[wid], s1 = off[wid + 1];
  float2* op = (float2*)(out + (size_t)wid * 128) + lane;
  float2 r = *op;  // prefetch RMW operand early
  float a0 = 0.f, a1 = 0.f;
  for (int base = s0; base < s1; base += 64) {
    const int cnt = min(64, s1 - base);
    int my = (lane < cnt) ? csr[base + lane] : 0;
    int k = 0;
    for (; k + 8 <= cnt; k += 8) {
      int i0 = __shfl(my, k);
      int i1 = __shfl(my, k + 1);
      int i2 = __shfl(my, k + 2);
      int i3 = __shfl(my, k + 3);
      int i4 = __shfl(my, k + 4);
      int i5 = __shfl(my, k + 5);
      int i6 = __shfl(my, k + 6);
      int i7 = __shfl(my, k + 7);
      unsigned u0 = ((const unsigned*)(t + (size_t)i0 * 128))[lane];
      unsigned u1 = ((const unsigned*)(t + (size_t)i1 * 128))[lane];
      unsigned u2 = ((const unsigned*)(t + (size_t)i2 * 128))[lane];
      unsigned u3 = ((const unsigned*)(t + (size_t)i3 * 128))[lane];
      unsigned u4 = ((const unsigned*)(t + (size_t)i4 * 128))[lane];
      unsigned u5 = ((const unsigned*)(t + (size_t)i5 * 128))[lane];
      unsigned u6 = ((const unsigned*)(t + (size_t)i6 * 128))[lane];
      unsigned u7 = ((const unsigned*)(t + (size_t)i7 * 128))[lane];
      a0 += blo(u0); a1 += bhi(u0);
      a0 += blo(u1); a1 += bhi(u1);
      a0 += blo(u2); a1 += bhi(u2);
      a0 += blo(u3); a1 += bhi(u3);
      a0 += blo(u4); a1 += bhi(u4);
      a0 += blo(u5); a1 += bhi(u5);
      a0 += blo(u6); a1 += bhi(u6);
      a0 += blo(u7); a1 += bhi(u7);
    }
    for (; k + 2 <= cnt; k += 2) {
      int i0 = __shfl(my, k);
      int i1 = __shfl(my, k + 1);
      unsigned u0 = ((const unsigned*)(t + (size_t)i0 * 128))[lane];
      unsigned u1 = ((const unsigned*)(t + (size_t)i1 * 128))[lane];
      a0 += blo(u0); a1 += bhi(u0);
      a0 += blo(u1); a1 += bhi(u1);
    }
    if (k < cnt) {
      int i0 = __shfl(my, k);
      unsigned u0 = ((const unsigned*)(t + (size_t)i0 * 128))[lane];
      a0 += blo(u0); a1 += bhi(u0);
    }
  }
  const float inv = 1.0f / fmaxf((float)(s1 - s0), 1.0f);
  r.x += a0 * inv;
  r.y += a1 * inv;
  *op = r;
}

// Fused 2-layer bf16 MFMA GEMM, sequential W-residency. 512 thr = 8 waves;
// wave w owns rows 0..63 x cols [w*32, w*32+32). Phase A: wr=W1 frags (64
// VGPR, loaded once from L2), A-tile staged to LDS (LDA=264, conflict-free
// b128); H=relu(acc+b1) -> Hs (LDS). Reload wr=W2 frags; phase B: acc=Hs@W2.T;
// waves 0-3: tb=bf16(acc) (=h@W2l.T); waves 4-7: out=acc+b2 (fp32).
// 2 barriers; no global loads inside MFMA loops.
__global__ __launch_bounds__(512, 4)
void gemm_fused(const unsigned short* __restrict__ A, const unsigned short* __restrict__ Wc1,
                const unsigned short* __restrict__ Wc2,
                const float* __restrict__ b1, const float* __restrict__ b2,
                unsigned short* __restrict__ tb, float* __restrict__ out, int M) {
  constexpr int LDA = 264;
  __shared__ __align__(16) unsigned short As[64 * LDA];
  __shared__ __align__(16) unsigned short Hs[64 * LDA];
  const int t = threadIdx.x;
  const int lane = t & 63;
  const int wave = t >> 6;
  const int wn = wave * 32;
  const int l15 = lane & 15;
  const int quad = lane >> 4;
  const int m_blk = blockIdx.x * 64;

  // Resident W1 fragments: j = wn + nt*16 + l15, k = c*32 + quad*8.
  bf16x8 wr[2][8];
#pragma unroll
  for (int nt = 0; nt < 2; nt++) {
    const unsigned short* wp = Wc1 + (size_t)(wn + nt * 16 + l15) * 256 + quad * 8;
#pragma unroll
    for (int c = 0; c < 8; c++) wr[nt][c] = *(const bf16x8*)(wp + c * 32);
  }
  const float bv0 = b1[wn + l15];
  const float bv1 = b1[wn + 16 + l15];

  // Stage A tile (64 rows x 256 k = 32 KB).
#pragma unroll
  for (int i = 0; i < 4; i++) {
    int idx = t + 512 * i;
    int row = idx >> 5, cc = (idx & 31) * 8;
    int ar = m_blk + row;
    if (ar >= M) ar = M - 1;
    *(uint4*)(As + row * LDA + cc) = *(const uint4*)(A + (size_t)ar * 256 + cc);
  }
  __syncthreads();

  // ---- Phase A: acc = A @ Wc1.T ----
  floatx4 acc[4][2] = {};
#pragma unroll
  for (int c = 0; c < 8; c++) {
    bf16x8 af[4];
#pragma unroll
    for (int mt = 0; mt < 4; mt++)
      af[mt] = *(const bf16x8*)(As + (mt * 16 + l15) * LDA + c * 32 + quad * 8);
#pragma unroll
    for (int mt = 0; mt < 4; mt++) {
      acc[mt][0] = __builtin_amdgcn_mfma_f32_16x16x32_bf16(af[mt], wr[0][c], acc[mt][0], 0, 0, 0);
      acc[mt][1] = __builtin_amdgcn_mfma_f32_16x16x32_bf16(af[mt], wr[1][c], acc[mt][1], 0, 0, 0);
    }
  }

  // Epilogue A: H = relu(acc + b1) into Hs.
#pragma unroll
  for (int mt = 0; mt < 4; mt++) {
#pragma unroll
    for (int nt = 0; nt < 2; nt++) {
      const int jl = wn + nt * 16 + l15;
      const float bv = nt ? bv1 : bv0;
#pragma unroll
      for (int r = 0; r < 4; r++) {
        const int row = mt * 16 + quad * 4 + r;
        Hs[row * LDA + jl] = f2b(fmaxf(acc[mt][nt][r] + bv, 0.f));
      }
    }
  }

  // Reload wr with W2 fragments (independent of Hs; overlaps other waves'
  // epilogue work before the barrier).
#pragma unroll
  for (int nt = 0; nt < 2; nt++) {
    const unsigned short* wp = Wc2 + (size_t)(wn + nt * 16 + l15) * 256 + quad * 8;
#pragma unroll
    for (int c = 0; c < 8; c++) wr[nt][c] = *(const bf16x8*)(wp + c * 32);
  }
  const float cv0 = (wn >= 128) ? b2[wn - 128 + l15] : 0.f;
  const float cv1 = (wn >= 128) ? b2[wn - 112 + l15] : 0.f;
  __syncthreads();

  // ---- Phase B: acc = Hs @ Wc2.T ----
#pragma unroll
  for (int mt = 0; mt < 4; mt++) {
    acc[mt][0] = (floatx4){0.f, 0.f, 0.f, 0.f};
    acc[mt][1] = (floatx4){0.f, 0.f, 0.f, 0.f};
  }
#pragma unroll
  for (int c = 0; c < 8; c++) {
    bf16x8 af[4];
#pragma unroll
    for (int mt = 0; mt < 4; mt++)
      af[mt] = *(const bf16x8*)(Hs + (mt * 16 + l15) * LDA + c * 32 + quad * 8);
#pragma unroll
    for (int mt = 0; mt < 4; mt++) {
      acc[mt][0] = __builtin_amdgcn_mfma_f32_16x16x32_bf16(af[mt], wr[0][c], acc[mt][0], 0, 0, 0);
      acc[mt][1] = __builtin_amdgcn_mfma_f32_16x16x32_bf16(af[mt], wr[1][c], acc[mt][1], 0, 0, 0);
    }
  }

  // Epilogue B: waves 0-3 (j<128) -> tb bf16; waves 4-7 -> out fp32 + bias.
#pragma unroll
  for (int mt = 0; mt < 4; mt++) {
#pragma unroll
    for (int nt = 0; nt < 2; nt++) {
      const int j = wn + nt * 16 + l15;
      const float bv = nt ? cv1 : cv0;
#pragma unroll
      for (int r = 0; r < 4; r++) {
        const int node = m_blk + mt * 16 + quad * 4 + r;
        if (node >= M) continue;
        const float v = acc[mt][nt][r];
        if (j < 128) {
          tb[(size_t)node * 128 + j] = f2b(v);
        } else {
          out[(size_t)node * 128 + (j - 128)] = v + bv;
        }
      }
    }
  }
}

extern "C" void kernel_launch(void* const* d_in, const int* in_sizes, int n_in,
                              void* d_out, int out_size, void* d_ws, size_t ws_size,
                              hipStream_t stream) {
  const float* x   = (const float*)d_in[0];
  const int*  eidx = (const int*)d_in[1];
  const float* W1l = (const float*)d_in[2];
  const float* b1l = (const float*)d_in[3];
  const float* W1r = (const float*)d_in[4];
  const float* W2l = (const float*)d_in[5];
  const float* b2l = (const float*)d_in[6];
  const float* W2r = (const float*)d_in[7];
  float* out = (float*)d_out;

  const int N = in_sizes[0] / 128;
  const int E = in_sizes[1] / 2;
  const int* src = eidx;
  const int* dst = eidx + E;

  int* cnt  = (int*)d_ws;          // [N]
  int* off  = cnt + N;             // [N+1]
  int* bsum = off + N + 1;         // [64]
  int* rank = bsum + 64;           // [E]
  int* csr  = rank + E;            // [E]
  size_t ioff = ((size_t)(N + N + 1 + 64 + 2 * E) * 4 + 15) & ~(size_t)15;
  unsigned short* A1  = (unsigned short*)((char*)d_ws + ioff);  // [N][256]
  unsigned short* tb  = A1 + (size_t)N * 256;                   // [N][128]
  unsigned short* Wc1 = tb + (size_t)N * 128;                   // [256][256]
  unsigned short* Wc2 = Wc1 + 65536;                            // [256][256]

  const int SB = (N + 1023) / 1024;  // 49

  prep_kernel<<<(N * 32 + 255) / 256, 256, 0, stream>>>(x, W1l, W1r, W2l, W2r,
                                                        Wc1, Wc2, A1, cnt, off, N, E);
  hist_kernel<<<(E / 4 + 255) / 256, 256, 0, stream>>>(dst, cnt, rank, E);
  scan_blocks_kernel<<<SB, 1024, 0, stream>>>(cnt, off, bsum, N);
  scan_add_kernel<<<SB, 1024, 0, stream>>>(off, bsum, N, SB);
  fill_kernel<<<(E / 4 + 255) / 256, 256, 0, stream>>>(src, dst, rank, off, csr, E);

  const int gblocks = (N + 3) / 4;  // 1 wave (64 lanes) per node
  gather1_kernel<<<gblocks, 256, 0, stream>>>(A1 + 128, csr, off, A1, N);

  gemm_fused<<<(N + 63) / 64, 512, 0, stream>>>(A1, Wc1, Wc2, b1l, b2l, tb, out, N);

  gather2_kernel<<<gblocks, 256, 0, stream>>>(tb, csr, off, out, N);
}